// Round 1
// baseline (602.524 us; speedup 1.0000x reference)
//
#include <hip/hip_runtime.h>
#include <stdint.h>

// Problem constants (S,M,H,E fixed by setup_inputs; C = ceil(K*S/E) aligned to 4 = 1024)
#define S_TOK 4096
#define MDIM  1024
#define HDIM  4096
#define NEXP  8
#define CAP   1024

typedef __attribute__((ext_vector_type(4))) float f4;
typedef __attribute__((ext_vector_type(8))) short short8;
typedef __attribute__((ext_vector_type(4))) unsigned short us4;
typedef __attribute__((ext_vector_type(8))) unsigned short us8;

__device__ __forceinline__ unsigned short f2bf(float f) {
  union { float f; unsigned int u; } v; v.f = f;
  unsigned int u = v.u;
  unsigned int r = (u + 0x7FFFu + ((u >> 16) & 1u)) >> 16;  // RNE
  return (unsigned short)r;
}

// async global->LDS, 16B per lane; LDS dest = wave-uniform base + lane*16
__device__ __forceinline__ void async16(const unsigned short* gp, unsigned short* lp_wave_base) {
  __builtin_amdgcn_global_load_lds(
      (const __attribute__((address_space(1))) unsigned int*)gp,
      (__attribute__((address_space(3))) unsigned int*)lp_wave_base,
      16, 0, 0);
}

// ---------------- gating: logits (fp32), softmax, top-2, gates ----------------
__global__ __launch_bounds__(256) void gating_kernel(
    const float* __restrict__ x, const float* __restrict__ wg,
    float* __restrict__ scores, int* __restrict__ topk_ids,
    float* __restrict__ gates)
{
  int wave = threadIdx.x >> 6, lane = threadIdx.x & 63;
  int s = blockIdx.x * 4 + wave;
  const float* xs = x + (size_t)s * MDIM;
  float acc[8];
#pragma unroll
  for (int e = 0; e < 8; ++e) acc[e] = 0.f;
#pragma unroll
  for (int j = 0; j < 4; ++j) {
    f4 xv = *(const f4*)(xs + j * 256 + lane * 4);
#pragma unroll
    for (int i = 0; i < 4; ++i) {
      int m = j * 256 + lane * 4 + i;
      const f4* w = (const f4*)(wg + (size_t)m * 8);
      f4 w0 = w[0], w1 = w[1];
      acc[0] += xv[i] * w0[0]; acc[1] += xv[i] * w0[1];
      acc[2] += xv[i] * w0[2]; acc[3] += xv[i] * w0[3];
      acc[4] += xv[i] * w1[0]; acc[5] += xv[i] * w1[1];
      acc[6] += xv[i] * w1[2]; acc[7] += xv[i] * w1[3];
    }
  }
#pragma unroll
  for (int e = 0; e < 8; ++e) {
    float v = acc[e];
    for (int off = 32; off; off >>= 1) v += __shfl_xor(v, off, 64);
    acc[e] = v;
  }
  if (lane == 0) {
    float mx = acc[0];
#pragma unroll
    for (int e = 1; e < 8; ++e) mx = fmaxf(mx, acc[e]);
    float p[8], tot = 0.f;
#pragma unroll
    for (int e = 0; e < 8; ++e) { p[e] = expf(acc[e] - mx); tot += p[e]; }
    float inv = 1.f / tot;
#pragma unroll
    for (int e = 0; e < 8; ++e) { p[e] *= inv; scores[s * 8 + e] = p[e]; }
    // top-2 with lowest-index tie-break (strict >), matching lax.top_k
    int i0 = 0;
#pragma unroll
    for (int e = 1; e < 8; ++e) if (p[e] > p[i0]) i0 = e;
    int i1 = -1;
#pragma unroll
    for (int e = 0; e < 8; ++e) {
      if (e == i0) continue;
      if (i1 < 0 || p[e] > p[i1]) i1 = e;
    }
    float v0 = p[i0], v1 = p[i1];
    float den = fmaxf(v0 + v1, 1e-7f);
    topk_ids[s * 2] = i0; topk_ids[s * 2 + 1] = i1;
    gates[s * 2] = v0 / den; gates[s * 2 + 1] = v1 / den;
  }
}

// ---------- assignment: exact ordered capacity scan (k-major over 8192 entries) ----------
// Outputs per expert-row: row_src (source token or -1), row_gate (combine weight).
__global__ __launch_bounds__(1024) void assign_kernel(
    const int* __restrict__ topk_ids, const float* __restrict__ gates,
    int* __restrict__ row_src, float* __restrict__ row_gate)
{
  __shared__ unsigned long long sc0[1024], sc1[1024];
  int t = threadIdx.x;
#pragma unroll
  for (int j = 0; j < 8; ++j) row_src[t * 8 + j] = -1;  // all 8192 rows

  int e8[8];
  unsigned long long c0 = 0, c1 = 0;
  int base = t * 8;
#pragma unroll
  for (int j = 0; j < 8; ++j) {
    int i = base + j;
    int k = i >> 12, s = i & 4095;     // i = k*4096 + s (k-major = reference offset order)
    int e = topk_ids[s * 2 + k];
    e8[j] = e;
    if (e < 4) c0 += 1ull << (16 * e); else c1 += 1ull << (16 * (e - 4));
  }
  sc0[t] = c0; sc1[t] = c1;
  __syncthreads();
  for (int off = 1; off < 1024; off <<= 1) {
    unsigned long long a0 = 0, a1 = 0;
    if (t >= off) { a0 = sc0[t - off]; a1 = sc1[t - off]; }
    __syncthreads();
    sc0[t] += a0; sc1[t] += a1;
    __syncthreads();
  }
  unsigned long long r0 = 0, r1 = 0;
  if (t > 0) { r0 = sc0[t - 1]; r1 = sc1[t - 1]; }
#pragma unroll
  for (int j = 0; j < 8; ++j) {
    int i = base + j;
    int k = i >> 12, s = i & 4095;
    int e = e8[j];
    int loc = (e < 4) ? (int)((r0 >> (16 * e)) & 0xFFFFull)
                      : (int)((r1 >> (16 * (e - 4))) & 0xFFFFull);
    if (e < 4) r0 += 1ull << (16 * e); else r1 += 1ull << (16 * (e - 4));
    if (loc < CAP) {
      int flat = e * CAP + loc;
      row_src[flat] = s;
      row_gate[flat] = gates[s * 2 + k];
    }
  }
}

// ---------------- dispatch: y[row] = bf16(x[src]) or zeros; 2 rows per block ----------------
__global__ __launch_bounds__(256) void dispatch_kernel(
    const float* __restrict__ x, const int* __restrict__ row_src,
    unsigned short* __restrict__ y)
{
  int r = blockIdx.x * 2 + (threadIdx.x >> 7);
  int s = row_src[r];
  int m0 = (threadIdx.x & 127) * 8;
  us8 o;
  if (s >= 0) {
    f4 v0 = *(const f4*)(x + (size_t)s * MDIM + m0);
    f4 v1 = *(const f4*)(x + (size_t)s * MDIM + m0 + 4);
#pragma unroll
    for (int i = 0; i < 4; ++i) { o[i] = f2bf(v0[i]); o[4 + i] = f2bf(v1[i]); }
  } else {
#pragma unroll
    for (int i = 0; i < 8; ++i) o[i] = 0;
  }
  *(us8*)(y + (size_t)r * MDIM + m0) = o;
}

// -------- weight convert+transpose: in [E,R,Cc] fp32 -> out [E,Cc,R] bf16 --------
// 64x64 tile staged as fp32 in LDS (stride 68 words, f4 16B-aligned bank-balanced writes);
// transposed b32 reads + convert + us8 (16B) coalesced stores.
__global__ __launch_bounds__(256) void convT_kernel(
    const float* __restrict__ in, unsigned short* __restrict__ out,
    int R, int Cc)
{
  __shared__ float tile[64 * 68];
  int e = blockIdx.z;
  int c0 = blockIdx.x * 64, r0 = blockIdx.y * 64;
  int t = threadIdx.x;
  const float* ine = in + (size_t)e * R * Cc;
  unsigned short* oute = out + (size_t)e * Cc * R;

  int cg = t & 15, rr = t >> 4;  // load map: 16 col-groups of 4 floats x 16 rows
#pragma unroll
  for (int p = 0; p < 4; ++p) {
    int r = rr + 16 * p;
    f4 v = *(const f4*)(ine + (size_t)(r0 + r) * Cc + c0 + cg * 4);
    *(f4*)&tile[r * 68 + cg * 4] = v;
  }
  __syncthreads();
  int c = t >> 3, rb = t & 7;    // store map: 32 cols x 8 r-chunks per pass
#pragma unroll
  for (int p = 0; p < 2; ++p) {
    int cc = c + 32 * p;
    us8 o;
#pragma unroll
    for (int i = 0; i < 8; ++i) o[i] = f2bf(tile[(rb * 8 + i) * 68 + cc]);
    *(us8*)(oute + (size_t)(c0 + cc) * R + r0 + rb * 8) = o;
  }
}

// ---------------- bf16 MFMA GEMM, B^T operand, expert-batched, XCD-swizzled ----------------
// 1D grid; e = lin&7 pins each expert's blocks to one XCD (L2 locality heuristic).
// ksplit_log2: split-K factor (fused path only); each block accumulates K>>ksplit_log2.
// fuse=0: out bf16 = (relu? max(v+b,0) : v+b), LDS-staged us8 stores.
// fuse=1: combine epilogue: atomicAdd(out[token, col], gate * (v+b)) using row_src/row_gate.
//         bias is applied only by the kh==0 block so it is added exactly once.
__global__ __launch_bounds__(256) void gemm_bt(
    const unsigned short* __restrict__ A, const unsigned short* __restrict__ Bt,
    const float* __restrict__ bias, unsigned short* __restrict__ Cout,
    int RA, int N, int K, int relu, int gxmask, int gxshift, int ksplit_log2,
    int fuse, const int* __restrict__ row_src, const float* __restrict__ row_gate,
    float* __restrict__ out)
{
  int lin = blockIdx.x;
  int e = lin & 7;
  int t2 = lin >> 3;
  int kh = t2 & ((1 << ksplit_log2) - 1);
  int tt = t2 >> ksplit_log2;
  int bCol = (tt & gxmask) * 128;
  int bRow = (tt >> gxshift) * 128;
  int Kblk = K >> ksplit_log2;
  int kBase = kh * Kblk;

  const unsigned short* Ae = A  + (size_t)e * RA * K;
  const unsigned short* Be = Bt + (size_t)e * N  * K;
  const float* be = bias + (size_t)e * N;

  __shared__ __align__(16) unsigned short LDSbuf[16384];  // 32KB
  unsigned short* Atile[2] = { LDSbuf,        LDSbuf + 4096 };
  unsigned short* Btile[2] = { LDSbuf + 8192, LDSbuf + 12288 };

  int tid = threadIdx.x;
  int lane = tid & 63, wave = tid >> 6;
  int wr = wave >> 1, wc = wave & 1;
  int q = lane >> 4, r16 = lane & 15;

  f4 acc[4][4] = {};

  for (int k0 = kBase; k0 < kBase + Kblk; k0 += 64) {
#pragma unroll
    for (int ks = 0; ks < 2; ++ks)
#pragma unroll
      for (int t = 0; t < 2; ++t) {
        int ci = (wave * 2 + t) * 64 + lane;          // chunk id in [0,512)
        int row = ci >> 2, c8 = (ci & 3) * 8;
        async16(Ae + (size_t)(bRow + row) * K + k0 + ks * 32 + c8, Atile[ks] + (wave * 2 + t) * 512);
        async16(Be + (size_t)(bCol + row) * K + k0 + ks * 32 + c8, Btile[ks] + (wave * 2 + t) * 512);
      }
    __syncthreads();
#pragma unroll
    for (int ks = 0; ks < 2; ++ks) {
      short8 af[4], bf[4];
#pragma unroll
      for (int mt = 0; mt < 4; ++mt)
        af[mt] = *(const short8*)&Atile[ks][(wr * 64 + mt * 16 + r16) * 32 + q * 8];
#pragma unroll
      for (int nt = 0; nt < 4; ++nt)
        bf[nt] = *(const short8*)&Btile[ks][(wc * 64 + nt * 16 + r16) * 32 + q * 8];
#pragma unroll
      for (int mt = 0; mt < 4; ++mt)
#pragma unroll
        for (int nt = 0; nt < 4; ++nt)
          acc[mt][nt] = __builtin_amdgcn_mfma_f32_16x16x32_bf16(af[mt], bf[nt], acc[mt][nt], 0, 0, 0);
    }
    __syncthreads();
  }

  // C/D layout: col=lane&15, row=quad*4+reg (verified m89/m91)
  float bv[4];
#pragma unroll
  for (int nt = 0; nt < 4; ++nt) bv[nt] = (kh == 0) ? be[bCol + wc * 64 + nt * 16 + r16] : 0.f;

  if (!fuse) {
    // stage wave's 64x64 bf16 tile in its private LDS quadrant, then 16B stores
    unsigned short* ep = LDSbuf + wave * 4096;
#pragma unroll
    for (int mt = 0; mt < 4; ++mt)
#pragma unroll
      for (int nt = 0; nt < 4; ++nt)
#pragma unroll
        for (int r = 0; r < 4; ++r) {
          float v = acc[mt][nt][r] + bv[nt];
          if (relu) v = fmaxf(v, 0.f);
          ep[(mt * 16 + q * 4 + r) * 64 + nt * 16 + r16] = f2bf(v);
        }
#pragma unroll
    for (int rb = 0; rb < 8; ++rb) {
      int row = rb * 8 + (lane >> 3);
      int seg = lane & 7;
      us8 v = *(const us8*)&ep[row * 64 + seg * 8];
      *(us8*)&Cout[((size_t)e * RA + bRow + wr * 64 + row) * N + bCol + wc * 64 + seg * 8] = v;
    }
  } else {
    // fused combine: each expert row -> token s with gate g; out[s] += g * (acc + bias)
#pragma unroll
    for (int mt = 0; mt < 4; ++mt)
#pragma unroll
      for (int r = 0; r < 4; ++r) {
        int grow = e * RA + bRow + wr * 64 + mt * 16 + q * 4 + r;
        int s = row_src[grow];
        if (s < 0) continue;
        float g = row_gate[grow];
#pragma unroll
        for (int nt = 0; nt < 4; ++nt) {
          float v = acc[mt][nt][r] + bv[nt];
          atomicAdd(out + (size_t)s * N + bCol + wc * 64 + nt * 16 + r16, g * v);
        }
      }
  }
}

// ---------------- l_aux: deterministic single-block reduction ----------------
__global__ __launch_bounds__(256) void aux_kernel(
    const float* __restrict__ scores, const int* __restrict__ topk_ids,
    float* __restrict__ laux_out)
{
  __shared__ float red[256];
  __shared__ float msum[8], csum[8];
  int t = threadIdx.x;
  float me[8], ce[8];
#pragma unroll
  for (int e = 0; e < 8; ++e) { me[e] = 0.f; ce[e] = 0.f; }
  for (int s = t; s < S_TOK; s += 256) {
#pragma unroll
    for (int e = 0; e < 8; ++e) me[e] += scores[s * 8 + e];
    int top = topk_ids[s * 2];
#pragma unroll
    for (int e = 0; e < 8; ++e) ce[e] += (top == e) ? 1.f : 0.f;
  }
  for (int e = 0; e < 8; ++e) {
    red[t] = me[e]; __syncthreads();
    for (int off = 128; off; off >>= 1) { if (t < off) red[t] += red[t + off]; __syncthreads(); }
    if (t == 0) msum[e] = red[0];
    __syncthreads();
  }
  for (int e = 0; e < 8; ++e) {
    red[t] = ce[e]; __syncthreads();
    for (int off = 128; off; off >>= 1) { if (t < off) red[t] += red[t + off]; __syncthreads(); }
    if (t == 0) csum[e] = red[0];
    __syncthreads();
  }
  if (t == 0) {
    float l = 0.f;
#pragma unroll
    for (int e = 0; e < 8; ++e)
      l += (msum[e] / (float)S_TOK) * (csum[e] / (float)S_TOK);
    laux_out[0] = l * (float)NEXP;
  }
}

extern "C" void kernel_launch(void* const* d_in, const int* in_sizes, int n_in,
                              void* d_out, int out_size, void* d_ws, size_t ws_size,
                              hipStream_t stream) {
  const float* x     = (const float*)d_in[0];
  const float* wg    = (const float*)d_in[1];
  const float* fc1_w = (const float*)d_in[2];
  const float* fc1_b = (const float*)d_in[3];
  const float* fc2_w = (const float*)d_in[4];
  const float* fc2_b = (const float*)d_in[5];
  float* out = (float*)d_out;

  // workspace carve-out (~208 MB total)
  char* ws = (char*)d_ws;
  size_t off = 0;
  auto alloc = [&](size_t b) { size_t o = off; off += (b + 255) & ~(size_t)255; return o; };
  unsigned short* fc1T = (unsigned short*)(ws + alloc((size_t)NEXP * HDIM * MDIM * 2)); // [E,H,M] bf16
  unsigned short* fc2T = (unsigned short*)(ws + alloc((size_t)NEXP * MDIM * HDIM * 2)); // [E,M,H] bf16
  unsigned short* y    = (unsigned short*)(ws + alloc((size_t)NEXP * CAP * MDIM * 2));  // [E*C,M] bf16
  unsigned short* h    = (unsigned short*)(ws + alloc((size_t)NEXP * CAP * HDIM * 2));  // [E*C,H] bf16
  float* scores        = (float*)(ws + alloc((size_t)S_TOK * 8 * 4));
  int*   topk          = (int*)(ws + alloc((size_t)S_TOK * 2 * 4));
  float* gates         = (float*)(ws + alloc((size_t)S_TOK * 2 * 4));
  int*   row_src       = (int*)(ws + alloc((size_t)NEXP * CAP * 4));
  float* row_gate      = (float*)(ws + alloc((size_t)NEXP * CAP * 4));

  // zero-init output (combine epilogue accumulates atomically into it)
  hipMemsetAsync(d_out, 0, (size_t)out_size * 4, stream);

  // fc1_w [E,M,H] -> fc1T [E,H,M]  (so it's L3-hot for GEMM1)
  convT_kernel<<<dim3(HDIM / 64, MDIM / 64, NEXP), 256, 0, stream>>>(fc1_w, fc1T, MDIM, HDIM);

  gating_kernel<<<dim3(S_TOK / 4), 256, 0, stream>>>(x, wg, scores, topk, gates);
  assign_kernel<<<dim3(1), 1024, 0, stream>>>(topk, gates, row_src, row_gate);
  dispatch_kernel<<<dim3(NEXP * CAP / 2), 256, 0, stream>>>(x, row_src, y);

  // h = relu(y @ fc1_w + fc1_b): RA=C, N=H, K=M; grid 32x8x8 -> 2048 blocks 1D
  gemm_bt<<<dim3(2048), 256, 0, stream>>>(y, fc1T, fc1_b, h, CAP, HDIM, MDIM, 1, 31, 5, 0,
                                          0, nullptr, nullptr, nullptr);

  // fc2_w [E,H,M] -> fc2T [E,M,H]  (L3-hot for GEMM2)
  convT_kernel<<<dim3(MDIM / 64, HDIM / 64, NEXP), 256, 0, stream>>>(fc2_w, fc2T, HDIM, MDIM);

  // out[token] += gate * (h @ fc2_w + fc2_b): RA=C, N=M, K=H; split-K=2 -> grid 1024 (4 blk/CU)
  gemm_bt<<<dim3(1024), 256, 0, stream>>>(h, fc2T, fc2_b, nullptr, CAP, MDIM, HDIM, 0, 7, 3, 1,
                                          1, row_src, row_gate, out);

  aux_kernel<<<dim3(1), 256, 0, stream>>>(scores, topk, out + (size_t)S_TOK * MDIM);
}

// Round 2
// 534.623 us; speedup vs baseline: 1.1270x; 1.1270x over previous
//
#include <hip/hip_runtime.h>
#include <stdint.h>

// Problem constants (S,M,H,E fixed by setup_inputs; C = ceil(K*S/E) aligned to 4 = 1024)
#define S_TOK 4096
#define MDIM  1024
#define HDIM  4096
#define NEXP  8
#define CAP   1024

typedef __attribute__((ext_vector_type(4))) float f4;
typedef __attribute__((ext_vector_type(8))) short short8;
typedef __attribute__((ext_vector_type(4))) unsigned short us4;
typedef __attribute__((ext_vector_type(8))) unsigned short us8;

__device__ __forceinline__ unsigned short f2bf(float f) {
  union { float f; unsigned int u; } v; v.f = f;
  unsigned int u = v.u;
  unsigned int r = (u + 0x7FFFu + ((u >> 16) & 1u)) >> 16;  // RNE
  return (unsigned short)r;
}

// async global->LDS, 16B per lane; LDS dest = wave-uniform base + lane*16
__device__ __forceinline__ void async16(const unsigned short* gp, unsigned short* lp_wave_base) {
  __builtin_amdgcn_global_load_lds(
      (const __attribute__((address_space(1))) unsigned int*)gp,
      (__attribute__((address_space(3))) unsigned int*)lp_wave_base,
      16, 0, 0);
}

// ---------------- gating: logits (fp32), softmax, top-2, gates ----------------
__global__ __launch_bounds__(256) void gating_kernel(
    const float* __restrict__ x, const float* __restrict__ wg,
    float* __restrict__ scores, int* __restrict__ topk_ids,
    float* __restrict__ gates)
{
  int wave = threadIdx.x >> 6, lane = threadIdx.x & 63;
  int s = blockIdx.x * 4 + wave;
  const float* xs = x + (size_t)s * MDIM;
  float acc[8];
#pragma unroll
  for (int e = 0; e < 8; ++e) acc[e] = 0.f;
#pragma unroll
  for (int j = 0; j < 4; ++j) {
    f4 xv = *(const f4*)(xs + j * 256 + lane * 4);
#pragma unroll
    for (int i = 0; i < 4; ++i) {
      int m = j * 256 + lane * 4 + i;
      const f4* w = (const f4*)(wg + (size_t)m * 8);
      f4 w0 = w[0], w1 = w[1];
      acc[0] += xv[i] * w0[0]; acc[1] += xv[i] * w0[1];
      acc[2] += xv[i] * w0[2]; acc[3] += xv[i] * w0[3];
      acc[4] += xv[i] * w1[0]; acc[5] += xv[i] * w1[1];
      acc[6] += xv[i] * w1[2]; acc[7] += xv[i] * w1[3];
    }
  }
#pragma unroll
  for (int e = 0; e < 8; ++e) {
    float v = acc[e];
    for (int off = 32; off; off >>= 1) v += __shfl_xor(v, off, 64);
    acc[e] = v;
  }
  if (lane == 0) {
    float mx = acc[0];
#pragma unroll
    for (int e = 1; e < 8; ++e) mx = fmaxf(mx, acc[e]);
    float p[8], tot = 0.f;
#pragma unroll
    for (int e = 0; e < 8; ++e) { p[e] = expf(acc[e] - mx); tot += p[e]; }
    float inv = 1.f / tot;
#pragma unroll
    for (int e = 0; e < 8; ++e) { p[e] *= inv; scores[s * 8 + e] = p[e]; }
    // top-2 with lowest-index tie-break (strict >), matching lax.top_k
    int i0 = 0;
#pragma unroll
    for (int e = 1; e < 8; ++e) if (p[e] > p[i0]) i0 = e;
    int i1 = -1;
#pragma unroll
    for (int e = 0; e < 8; ++e) {
      if (e == i0) continue;
      if (i1 < 0 || p[e] > p[i1]) i1 = e;
    }
    float v0 = p[i0], v1 = p[i1];
    float den = fmaxf(v0 + v1, 1e-7f);
    topk_ids[s * 2] = i0; topk_ids[s * 2 + 1] = i1;
    gates[s * 2] = v0 / den; gates[s * 2 + 1] = v1 / den;
  }
}

// ---------- assignment: exact ordered capacity scan (k-major over 8192 entries) ----------
// Outputs per expert-row: row_src (source token or -1), row_gate (combine weight).
__global__ __launch_bounds__(1024) void assign_kernel(
    const int* __restrict__ topk_ids, const float* __restrict__ gates,
    int* __restrict__ row_src, float* __restrict__ row_gate)
{
  __shared__ unsigned long long sc0[1024], sc1[1024];
  int t = threadIdx.x;
#pragma unroll
  for (int j = 0; j < 8; ++j) row_src[t * 8 + j] = -1;  // all 8192 rows

  int e8[8];
  unsigned long long c0 = 0, c1 = 0;
  int base = t * 8;
#pragma unroll
  for (int j = 0; j < 8; ++j) {
    int i = base + j;
    int k = i >> 12, s = i & 4095;     // i = k*4096 + s (k-major = reference offset order)
    int e = topk_ids[s * 2 + k];
    e8[j] = e;
    if (e < 4) c0 += 1ull << (16 * e); else c1 += 1ull << (16 * (e - 4));
  }
  sc0[t] = c0; sc1[t] = c1;
  __syncthreads();
  for (int off = 1; off < 1024; off <<= 1) {
    unsigned long long a0 = 0, a1 = 0;
    if (t >= off) { a0 = sc0[t - off]; a1 = sc1[t - off]; }
    __syncthreads();
    sc0[t] += a0; sc1[t] += a1;
    __syncthreads();
  }
  unsigned long long r0 = 0, r1 = 0;
  if (t > 0) { r0 = sc0[t - 1]; r1 = sc1[t - 1]; }
#pragma unroll
  for (int j = 0; j < 8; ++j) {
    int i = base + j;
    int k = i >> 12, s = i & 4095;
    int e = e8[j];
    int loc = (e < 4) ? (int)((r0 >> (16 * e)) & 0xFFFFull)
                      : (int)((r1 >> (16 * (e - 4))) & 0xFFFFull);
    if (e < 4) r0 += 1ull << (16 * e); else r1 += 1ull << (16 * (e - 4));
    if (loc < CAP) {
      int flat = e * CAP + loc;
      row_src[flat] = s;
      row_gate[flat] = gates[s * 2 + k];
    }
  }
}

// ---------------- dispatch: y[row] = bf16(x[src]) or zeros; 2 rows per block ----------------
__global__ __launch_bounds__(256) void dispatch_kernel(
    const float* __restrict__ x, const int* __restrict__ row_src,
    unsigned short* __restrict__ y)
{
  int r = blockIdx.x * 2 + (threadIdx.x >> 7);
  int s = row_src[r];
  int m0 = (threadIdx.x & 127) * 8;
  us8 o;
  if (s >= 0) {
    f4 v0 = *(const f4*)(x + (size_t)s * MDIM + m0);
    f4 v1 = *(const f4*)(x + (size_t)s * MDIM + m0 + 4);
#pragma unroll
    for (int i = 0; i < 4; ++i) { o[i] = f2bf(v0[i]); o[4 + i] = f2bf(v1[i]); }
  } else {
#pragma unroll
    for (int i = 0; i < 8; ++i) o[i] = 0;
  }
  *(us8*)(y + (size_t)r * MDIM + m0) = o;
}

// -------- weight convert+transpose: in [E,R,Cc] fp32 -> out [E,Cc,R] bf16 --------
// 64x64 tile staged as fp32 in LDS (stride 68 words, f4 16B-aligned bank-balanced writes);
// transposed b32 reads + convert + us8 (16B) coalesced stores.
// Weight reads are NON-TEMPORAL (`nt`): fp32 weights are stream-once; keep them from
// evicting the live L3 set (h / fc1T / fc2T / y) that the GEMMs depend on.
__global__ __launch_bounds__(256) void convT_kernel(
    const float* __restrict__ in, unsigned short* __restrict__ out,
    int R, int Cc)
{
  __shared__ float tile[64 * 68];
  int e = blockIdx.z;
  int c0 = blockIdx.x * 64, r0 = blockIdx.y * 64;
  int t = threadIdx.x;
  const float* ine = in + (size_t)e * R * Cc;
  unsigned short* oute = out + (size_t)e * Cc * R;

  int cg = t & 15, rr = t >> 4;  // load map: 16 col-groups of 4 floats x 16 rows
#pragma unroll
  for (int p = 0; p < 4; ++p) {
    int r = rr + 16 * p;
    f4 v = __builtin_nontemporal_load(
        (const f4*)(ine + (size_t)(r0 + r) * Cc + c0 + cg * 4));
    *(f4*)&tile[r * 68 + cg * 4] = v;
  }
  __syncthreads();
  int c = t >> 3, rb = t & 7;    // store map: 32 cols x 8 r-chunks per pass
#pragma unroll
  for (int p = 0; p < 2; ++p) {
    int cc = c + 32 * p;
    us8 o;
#pragma unroll
    for (int i = 0; i < 8; ++i) o[i] = f2bf(tile[(rb * 8 + i) * 68 + cc]);
    *(us8*)(oute + (size_t)(c0 + cc) * R + r0 + rb * 8) = o;
  }
}

// ---------------- bf16 MFMA GEMM, B^T operand, expert-batched, XCD-swizzled ----------------
// 1D grid; e = lin&7 pins each expert's blocks to one XCD (L2 locality heuristic).
// ksplit_log2: split-K factor (fused path only) — measured REGRESSION at 2 (r1: atomic
// traffic doubled, FETCH +55MB, dur +18us); launch with 0.
// fuse=0: out bf16 = (relu? max(v+b,0) : v+b), LDS-staged us8 stores.
// fuse=1: combine epilogue: atomicAdd(out[token, col], gate * (v+b)) using row_src/row_gate.
//         bias is applied only by the kh==0 block so it is added exactly once.
__global__ __launch_bounds__(256) void gemm_bt(
    const unsigned short* __restrict__ A, const unsigned short* __restrict__ Bt,
    const float* __restrict__ bias, unsigned short* __restrict__ Cout,
    int RA, int N, int K, int relu, int gxmask, int gxshift, int ksplit_log2,
    int fuse, const int* __restrict__ row_src, const float* __restrict__ row_gate,
    float* __restrict__ out)
{
  int lin = blockIdx.x;
  int e = lin & 7;
  int t2 = lin >> 3;
  int kh = t2 & ((1 << ksplit_log2) - 1);
  int tt = t2 >> ksplit_log2;
  int bCol = (tt & gxmask) * 128;
  int bRow = (tt >> gxshift) * 128;
  int Kblk = K >> ksplit_log2;
  int kBase = kh * Kblk;

  const unsigned short* Ae = A  + (size_t)e * RA * K;
  const unsigned short* Be = Bt + (size_t)e * N  * K;
  const float* be = bias + (size_t)e * N;

  __shared__ __align__(16) unsigned short LDSbuf[16384];  // 32KB
  unsigned short* Atile[2] = { LDSbuf,        LDSbuf + 4096 };
  unsigned short* Btile[2] = { LDSbuf + 8192, LDSbuf + 12288 };

  int tid = threadIdx.x;
  int lane = tid & 63, wave = tid >> 6;
  int wr = wave >> 1, wc = wave & 1;
  int q = lane >> 4, r16 = lane & 15;

  f4 acc[4][4] = {};

  for (int k0 = kBase; k0 < kBase + Kblk; k0 += 64) {
#pragma unroll
    for (int ks = 0; ks < 2; ++ks)
#pragma unroll
      for (int t = 0; t < 2; ++t) {
        int ci = (wave * 2 + t) * 64 + lane;          // chunk id in [0,512)
        int row = ci >> 2, c8 = (ci & 3) * 8;
        async16(Ae + (size_t)(bRow + row) * K + k0 + ks * 32 + c8, Atile[ks] + (wave * 2 + t) * 512);
        async16(Be + (size_t)(bCol + row) * K + k0 + ks * 32 + c8, Btile[ks] + (wave * 2 + t) * 512);
      }
    __syncthreads();
#pragma unroll
    for (int ks = 0; ks < 2; ++ks) {
      short8 af[4], bf[4];
#pragma unroll
      for (int mt = 0; mt < 4; ++mt)
        af[mt] = *(const short8*)&Atile[ks][(wr * 64 + mt * 16 + r16) * 32 + q * 8];
#pragma unroll
      for (int nt = 0; nt < 4; ++nt)
        bf[nt] = *(const short8*)&Btile[ks][(wc * 64 + nt * 16 + r16) * 32 + q * 8];
#pragma unroll
      for (int mt = 0; mt < 4; ++mt)
#pragma unroll
        for (int nt = 0; nt < 4; ++nt)
          acc[mt][nt] = __builtin_amdgcn_mfma_f32_16x16x32_bf16(af[mt], bf[nt], acc[mt][nt], 0, 0, 0);
    }
    __syncthreads();
  }

  // C/D layout: col=lane&15, row=quad*4+reg (verified m89/m91)
  float bv[4];
#pragma unroll
  for (int nt = 0; nt < 4; ++nt) bv[nt] = (kh == 0) ? be[bCol + wc * 64 + nt * 16 + r16] : 0.f;

  if (!fuse) {
    // stage wave's 64x64 bf16 tile in its private LDS quadrant, then 16B stores
    unsigned short* ep = LDSbuf + wave * 4096;
#pragma unroll
    for (int mt = 0; mt < 4; ++mt)
#pragma unroll
      for (int nt = 0; nt < 4; ++nt)
#pragma unroll
        for (int r = 0; r < 4; ++r) {
          float v = acc[mt][nt][r] + bv[nt];
          if (relu) v = fmaxf(v, 0.f);
          ep[(mt * 16 + q * 4 + r) * 64 + nt * 16 + r16] = f2bf(v);
        }
#pragma unroll
    for (int rb = 0; rb < 8; ++rb) {
      int row = rb * 8 + (lane >> 3);
      int seg = lane & 7;
      us8 v = *(const us8*)&ep[row * 64 + seg * 8];
      *(us8*)&Cout[((size_t)e * RA + bRow + wr * 64 + row) * N + bCol + wc * 64 + seg * 8] = v;
    }
  } else {
    // fused combine: each expert row -> token s with gate g; out[s] += g * (acc + bias)
#pragma unroll
    for (int mt = 0; mt < 4; ++mt)
#pragma unroll
      for (int r = 0; r < 4; ++r) {
        int grow = e * RA + bRow + wr * 64 + mt * 16 + q * 4 + r;
        int s = row_src[grow];
        if (s < 0) continue;
        float g = row_gate[grow];
#pragma unroll
        for (int nt = 0; nt < 4; ++nt) {
          float v = acc[mt][nt][r] + bv[nt];
          atomicAdd(out + (size_t)s * N + bCol + wc * 64 + nt * 16 + r16, g * v);
        }
      }
  }
}

// ---------------- l_aux: deterministic single-block reduction ----------------
__global__ __launch_bounds__(256) void aux_kernel(
    const float* __restrict__ scores, const int* __restrict__ topk_ids,
    float* __restrict__ laux_out)
{
  __shared__ float red[256];
  __shared__ float msum[8], csum[8];
  int t = threadIdx.x;
  float me[8], ce[8];
#pragma unroll
  for (int e = 0; e < 8; ++e) { me[e] = 0.f; ce[e] = 0.f; }
  for (int s = t; s < S_TOK; s += 256) {
#pragma unroll
    for (int e = 0; e < 8; ++e) me[e] += scores[s * 8 + e];
    int top = topk_ids[s * 2];
#pragma unroll
    for (int e = 0; e < 8; ++e) ce[e] += (top == e) ? 1.f : 0.f;
  }
  for (int e = 0; e < 8; ++e) {
    red[t] = me[e]; __syncthreads();
    for (int off = 128; off; off >>= 1) { if (t < off) red[t] += red[t + off]; __syncthreads(); }
    if (t == 0) msum[e] = red[0];
    __syncthreads();
  }
  for (int e = 0; e < 8; ++e) {
    red[t] = ce[e]; __syncthreads();
    for (int off = 128; off; off >>= 1) { if (t < off) red[t] += red[t + off]; __syncthreads(); }
    if (t == 0) csum[e] = red[0];
    __syncthreads();
  }
  if (t == 0) {
    float l = 0.f;
#pragma unroll
    for (int e = 0; e < 8; ++e)
      l += (msum[e] / (float)S_TOK) * (csum[e] / (float)S_TOK);
    laux_out[0] = l * (float)NEXP;
  }
}

extern "C" void kernel_launch(void* const* d_in, const int* in_sizes, int n_in,
                              void* d_out, int out_size, void* d_ws, size_t ws_size,
                              hipStream_t stream) {
  const float* x     = (const float*)d_in[0];
  const float* wg    = (const float*)d_in[1];
  const float* fc1_w = (const float*)d_in[2];
  const float* fc1_b = (const float*)d_in[3];
  const float* fc2_w = (const float*)d_in[4];
  const float* fc2_b = (const float*)d_in[5];
  float* out = (float*)d_out;

  // workspace carve-out (~208 MB total)
  char* ws = (char*)d_ws;
  size_t off = 0;
  auto alloc = [&](size_t b) { size_t o = off; off += (b + 255) & ~(size_t)255; return o; };
  unsigned short* fc1T = (unsigned short*)(ws + alloc((size_t)NEXP * HDIM * MDIM * 2)); // [E,H,M] bf16
  unsigned short* fc2T = (unsigned short*)(ws + alloc((size_t)NEXP * MDIM * HDIM * 2)); // [E,M,H] bf16
  unsigned short* y    = (unsigned short*)(ws + alloc((size_t)NEXP * CAP * MDIM * 2));  // [E*C,M] bf16
  unsigned short* h    = (unsigned short*)(ws + alloc((size_t)NEXP * CAP * HDIM * 2));  // [E*C,H] bf16
  float* scores        = (float*)(ws + alloc((size_t)S_TOK * 8 * 4));
  int*   topk          = (int*)(ws + alloc((size_t)S_TOK * 2 * 4));
  float* gates         = (float*)(ws + alloc((size_t)S_TOK * 2 * 4));
  int*   row_src       = (int*)(ws + alloc((size_t)NEXP * CAP * 4));
  float* row_gate      = (float*)(ws + alloc((size_t)NEXP * CAP * 4));

  // zero-init output (combine epilogue accumulates atomically into it)
  hipMemsetAsync(d_out, 0, (size_t)out_size * 4, stream);

  // fc1_w [E,M,H] -> fc1T [E,H,M]  (nt reads: don't pollute L3)
  convT_kernel<<<dim3(HDIM / 64, MDIM / 64, NEXP), 256, 0, stream>>>(fc1_w, fc1T, MDIM, HDIM);

  gating_kernel<<<dim3(S_TOK / 4), 256, 0, stream>>>(x, wg, scores, topk, gates);
  assign_kernel<<<dim3(1), 1024, 0, stream>>>(topk, gates, row_src, row_gate);
  dispatch_kernel<<<dim3(NEXP * CAP / 2), 256, 0, stream>>>(x, row_src, y);

  // h = relu(y @ fc1_w + fc1_b): RA=C, N=H, K=M; grid 32x8x8 -> 2048 blocks 1D
  gemm_bt<<<dim3(2048), 256, 0, stream>>>(y, fc1T, fc1_b, h, CAP, HDIM, MDIM, 1, 31, 5, 0,
                                          0, nullptr, nullptr, nullptr);

  // fc2_w [E,H,M] -> fc2T [E,M,H]  (nt reads: keep h L3-resident for GEMM2)
  convT_kernel<<<dim3(MDIM / 64, HDIM / 64, NEXP), 256, 0, stream>>>(fc2_w, fc2T, HDIM, MDIM);

  // out[token] += gate * (h @ fc2_w + fc2_b): RA=C, N=M, K=H; grid 8x8x8 -> 512 blocks 1D
  gemm_bt<<<dim3(512), 256, 0, stream>>>(h, fc2T, fc2_b, nullptr, CAP, MDIM, HDIM, 0, 7, 3, 0,
                                         1, row_src, row_gate, out);

  aux_kernel<<<dim3(1), 256, 0, stream>>>(scores, topk, out + (size_t)S_TOK * MDIM);
}

// Round 4
// 519.691 us; speedup vs baseline: 1.1594x; 1.0287x over previous
//
#include <hip/hip_runtime.h>
#include <stdint.h>

// Problem constants (S,M,H,E fixed by setup_inputs; C = ceil(K*S/E) aligned to 4 = 1024)
#define S_TOK 4096
#define MDIM  1024
#define HDIM  4096
#define NEXP  8
#define CAP   1024

typedef __attribute__((ext_vector_type(4))) float f4;
typedef __attribute__((ext_vector_type(8))) short short8;
typedef __attribute__((ext_vector_type(4))) unsigned short us4;
typedef __attribute__((ext_vector_type(8))) unsigned short us8;

__device__ __forceinline__ unsigned short f2bf(float f) {
  union { float f; unsigned int u; } v; v.f = f;
  unsigned int u = v.u;
  unsigned int r = (u + 0x7FFFu + ((u >> 16) & 1u)) >> 16;  // RNE
  return (unsigned short)r;
}

// async global->LDS, 16B per lane; LDS dest = wave-uniform base + lane*16
__device__ __forceinline__ void async16(const unsigned short* gp, unsigned short* lp_wave_base) {
  __builtin_amdgcn_global_load_lds(
      (const __attribute__((address_space(1))) unsigned int*)gp,
      (__attribute__((address_space(3))) unsigned int*)lp_wave_base,
      16, 0, 0);
}

// ---------------- gating: logits (fp32), softmax, top-2, gates ----------------
__global__ __launch_bounds__(256) void gating_kernel(
    const float* __restrict__ x, const float* __restrict__ wg,
    float* __restrict__ scores, int* __restrict__ topk_ids,
    float* __restrict__ gates)
{
  int wave = threadIdx.x >> 6, lane = threadIdx.x & 63;
  int s = blockIdx.x * 4 + wave;
  const float* xs = x + (size_t)s * MDIM;
  float acc[8];
#pragma unroll
  for (int e = 0; e < 8; ++e) acc[e] = 0.f;
#pragma unroll
  for (int j = 0; j < 4; ++j) {
    f4 xv = *(const f4*)(xs + j * 256 + lane * 4);
#pragma unroll
    for (int i = 0; i < 4; ++i) {
      int m = j * 256 + lane * 4 + i;
      const f4* w = (const f4*)(wg + (size_t)m * 8);
      f4 w0 = w[0], w1 = w[1];
      acc[0] += xv[i] * w0[0]; acc[1] += xv[i] * w0[1];
      acc[2] += xv[i] * w0[2]; acc[3] += xv[i] * w0[3];
      acc[4] += xv[i] * w1[0]; acc[5] += xv[i] * w1[1];
      acc[6] += xv[i] * w1[2]; acc[7] += xv[i] * w1[3];
    }
  }
#pragma unroll
  for (int e = 0; e < 8; ++e) {
    float v = acc[e];
    for (int off = 32; off; off >>= 1) v += __shfl_xor(v, off, 64);
    acc[e] = v;
  }
  if (lane == 0) {
    float mx = acc[0];
#pragma unroll
    for (int e = 1; e < 8; ++e) mx = fmaxf(mx, acc[e]);
    float p[8], tot = 0.f;
#pragma unroll
    for (int e = 0; e < 8; ++e) { p[e] = expf(acc[e] - mx); tot += p[e]; }
    float inv = 1.f / tot;
#pragma unroll
    for (int e = 0; e < 8; ++e) { p[e] *= inv; scores[s * 8 + e] = p[e]; }
    // top-2 with lowest-index tie-break (strict >), matching lax.top_k
    int i0 = 0;
#pragma unroll
    for (int e = 1; e < 8; ++e) if (p[e] > p[i0]) i0 = e;
    int i1 = -1;
#pragma unroll
    for (int e = 0; e < 8; ++e) {
      if (e == i0) continue;
      if (i1 < 0 || p[e] > p[i1]) i1 = e;
    }
    float v0 = p[i0], v1 = p[i1];
    float den = fmaxf(v0 + v1, 1e-7f);
    topk_ids[s * 2] = i0; topk_ids[s * 2 + 1] = i1;
    gates[s * 2] = v0 / den; gates[s * 2 + 1] = v1 / den;
  }
}

// ---------- assignment: exact ordered capacity scan (k-major over 8192 entries) ----------
// Outputs per expert-row: row_src (source token or -1), row_gate (combine weight).
__global__ __launch_bounds__(1024) void assign_kernel(
    const int* __restrict__ topk_ids, const float* __restrict__ gates,
    int* __restrict__ row_src, float* __restrict__ row_gate)
{
  __shared__ unsigned long long sc0[1024], sc1[1024];
  int t = threadIdx.x;
#pragma unroll
  for (int j = 0; j < 8; ++j) row_src[t * 8 + j] = -1;  // all 8192 rows

  int e8[8];
  unsigned long long c0 = 0, c1 = 0;
  int base = t * 8;
#pragma unroll
  for (int j = 0; j < 8; ++j) {
    int i = base + j;
    int k = i >> 12, s = i & 4095;     // i = k*4096 + s (k-major = reference offset order)
    int e = topk_ids[s * 2 + k];
    e8[j] = e;
    if (e < 4) c0 += 1ull << (16 * e); else c1 += 1ull << (16 * (e - 4));
  }
  sc0[t] = c0; sc1[t] = c1;
  __syncthreads();
  for (int off = 1; off < 1024; off <<= 1) {
    unsigned long long a0 = 0, a1 = 0;
    if (t >= off) { a0 = sc0[t - off]; a1 = sc1[t - off]; }
    __syncthreads();
    sc0[t] += a0; sc1[t] += a1;
    __syncthreads();
  }
  unsigned long long r0 = 0, r1 = 0;
  if (t > 0) { r0 = sc0[t - 1]; r1 = sc1[t - 1]; }
#pragma unroll
  for (int j = 0; j < 8; ++j) {
    int i = base + j;
    int k = i >> 12, s = i & 4095;
    int e = e8[j];
    int loc = (e < 4) ? (int)((r0 >> (16 * e)) & 0xFFFFull)
                      : (int)((r1 >> (16 * (e - 4))) & 0xFFFFull);
    if (e < 4) r0 += 1ull << (16 * e); else r1 += 1ull << (16 * (e - 4));
    if (loc < CAP) {
      int flat = e * CAP + loc;
      row_src[flat] = s;
      row_gate[flat] = gates[s * 2 + k];
    }
  }
}

// ---------------- dispatch: y[row] = bf16(x[src]) or zeros; 2 rows per block ----------------
__global__ __launch_bounds__(256) void dispatch_kernel(
    const float* __restrict__ x, const int* __restrict__ row_src,
    unsigned short* __restrict__ y)
{
  int r = blockIdx.x * 2 + (threadIdx.x >> 7);
  int s = row_src[r];
  int m0 = (threadIdx.x & 127) * 8;
  us8 o;
  if (s >= 0) {
    f4 v0 = *(const f4*)(x + (size_t)s * MDIM + m0);
    f4 v1 = *(const f4*)(x + (size_t)s * MDIM + m0 + 4);
#pragma unroll
    for (int i = 0; i < 4; ++i) { o[i] = f2bf(v0[i]); o[4 + i] = f2bf(v1[i]); }
  } else {
#pragma unroll
    for (int i = 0; i < 8; ++i) o[i] = 0;
  }
  *(us8*)(y + (size_t)r * MDIM + m0) = o;
}

// -------- weight convert+transpose: in [E,R,Cc] fp32 -> out [E,Cc,R] bf16 --------
// 64x64 tile staged as fp32 in LDS (stride 68 words, f4 16B-aligned bank-balanced writes);
// transposed b32 reads + convert + us8 (16B) coalesced stores.
// Weight reads are NON-TEMPORAL (`nt`): fp32 weights are stream-once; keep them from
// evicting the live L3 set (h / fc1T / fc2T / y) that the GEMMs depend on.
// (r2 measured: this was worth ~-44us total vs plain loads.)
__global__ __launch_bounds__(256) void convT_kernel(
    const float* __restrict__ in, unsigned short* __restrict__ out,
    int R, int Cc)
{
  __shared__ float tile[64 * 68];
  int e = blockIdx.z;
  int c0 = blockIdx.x * 64, r0 = blockIdx.y * 64;
  int t = threadIdx.x;
  const float* ine = in + (size_t)e * R * Cc;
  unsigned short* oute = out + (size_t)e * Cc * R;

  int cg = t & 15, rr = t >> 4;  // load map: 16 col-groups of 4 floats x 16 rows
#pragma unroll
  for (int p = 0; p < 4; ++p) {
    int r = rr + 16 * p;
    f4 v = __builtin_nontemporal_load(
        (const f4*)(ine + (size_t)(r0 + r) * Cc + c0 + cg * 4));
    *(f4*)&tile[r * 68 + cg * 4] = v;
  }
  __syncthreads();
  int c = t >> 3, rb = t & 7;    // store map: 32 cols x 8 r-chunks per pass
#pragma unroll
  for (int p = 0; p < 2; ++p) {
    int cc = c + 32 * p;
    us8 o;
#pragma unroll
    for (int i = 0; i < 8; ++i) o[i] = f2bf(tile[(rb * 8 + i) * 68 + cc]);
    *(us8*)(oute + (size_t)(c0 + cc) * R + r0 + rb * 8) = o;
  }
}

// ---------------- bf16 MFMA GEMM, B^T operand, expert-batched, XCD-swizzled ----------------
// 8 waves (512 threads) per 128x128 tile: wave grid 2(M)x4(N), each wave owns a 64x32
// sub-tile -> acc[4][2] = 32 AGPR + ~24 VGPR frags. With __launch_bounds__(512,4) total
// regs <=128 -> 4 waves/SIMD -> 2 blocks/CU = 16 waves/CU (50% occ) even at grid=2/CU.
// (r2 measured GEMM2 grid-capped at 8 waves/CU/22% occ with 4-wave blocks; split-K to
// raise grid was a measured regression in r1 -- this raises occupancy at fixed grid.)
// 1D grid; e = lin&7 pins each expert's blocks to one XCD (L2 locality heuristic).
// fuse=0: out bf16 = (relu? max(v+b,0) : v+b), LDS-staged us8 stores.
// fuse=1: combine epilogue: atomicAdd(out[token, col], gate * (v+b)) using row_src/row_gate.
__global__ __launch_bounds__(512, 4) void gemm_bt(
    const unsigned short* __restrict__ A, const unsigned short* __restrict__ Bt,
    const float* __restrict__ bias, unsigned short* __restrict__ Cout,
    int RA, int N, int K, int relu, int gxmask, int gxshift,
    int fuse, const int* __restrict__ row_src, const float* __restrict__ row_gate,
    float* __restrict__ out)
{
  int lin = blockIdx.x;
  int e = lin & 7;
  int tt = lin >> 3;
  int bCol = (tt & gxmask) * 128;
  int bRow = (tt >> gxshift) * 128;

  const unsigned short* Ae = A  + (size_t)e * RA * K;
  const unsigned short* Be = Bt + (size_t)e * N  * K;
  const float* be = bias + (size_t)e * N;

  __shared__ __align__(16) unsigned short LDSbuf[16384];  // 32KB
  unsigned short* Atile[2] = { LDSbuf,        LDSbuf + 4096 };
  unsigned short* Btile[2] = { LDSbuf + 8192, LDSbuf + 12288 };

  int tid = threadIdx.x;
  int lane = tid & 63, wave = tid >> 6;      // 8 waves
  int wr = wave >> 2, wc = wave & 3;         // 2 (M) x 4 (N)
  int q = lane >> 4, r16 = lane & 15;

  f4 acc[4][2] = {};

  for (int k0 = 0; k0 < K; k0 += 64) {
    // stage: per ks-half, 512 lanes x 16B cover the full 128x32 half-tile (8KB) of A and B.
    // chunk ci = wave*64+lane: row=ci>>2, k-offset=(ci&3)*8; LDS dest wave*512 + lane*8
    // shorts == row*32 + c8 (linear [row][k] layout, stride 32) -- wave-uniform-base rule ok.
#pragma unroll
    for (int ks = 0; ks < 2; ++ks) {
      int ci = wave * 64 + lane;
      int row = ci >> 2, c8 = (ci & 3) * 8;
      async16(Ae + (size_t)(bRow + row) * K + k0 + ks * 32 + c8, Atile[ks] + wave * 512);
      async16(Be + (size_t)(bCol + row) * K + k0 + ks * 32 + c8, Btile[ks] + wave * 512);
    }
    __syncthreads();
#pragma unroll
    for (int ks = 0; ks < 2; ++ks) {
      short8 af[4], bf[2];
#pragma unroll
      for (int mt = 0; mt < 4; ++mt)
        af[mt] = *(const short8*)&Atile[ks][(wr * 64 + mt * 16 + r16) * 32 + q * 8];
#pragma unroll
      for (int nt = 0; nt < 2; ++nt)
        bf[nt] = *(const short8*)&Btile[ks][(wc * 32 + nt * 16 + r16) * 32 + q * 8];
#pragma unroll
      for (int mt = 0; mt < 4; ++mt)
#pragma unroll
        for (int nt = 0; nt < 2; ++nt)
          acc[mt][nt] = __builtin_amdgcn_mfma_f32_16x16x32_bf16(af[mt], bf[nt], acc[mt][nt], 0, 0, 0);
    }
    __syncthreads();
  }

  // C/D layout: col=lane&15, row=quad*4+reg (verified m89/m91)
  float bv[2];
#pragma unroll
  for (int nt = 0; nt < 2; ++nt) bv[nt] = be[bCol + wc * 32 + nt * 16 + r16];

  if (!fuse) {
    // stage wave's 64x32 bf16 tile in its private 4KB LDS slice, then 16B stores
    unsigned short* ep = LDSbuf + wave * 2048;
#pragma unroll
    for (int mt = 0; mt < 4; ++mt)
#pragma unroll
      for (int nt = 0; nt < 2; ++nt)
#pragma unroll
        for (int r = 0; r < 4; ++r) {
          float v = acc[mt][nt][r] + bv[nt];
          if (relu) v = fmaxf(v, 0.f);
          ep[(mt * 16 + q * 4 + r) * 32 + nt * 16 + r16] = f2bf(v);
        }
    // 64 rows x 32 cols: 4 passes of 64 lanes x 16B
#pragma unroll
    for (int pass = 0; pass < 4; ++pass) {
      int row = pass * 16 + (lane >> 2);
      int seg = lane & 3;
      us8 v = *(const us8*)&ep[row * 32 + seg * 8];
      *(us8*)&Cout[((size_t)e * RA + bRow + wr * 64 + row) * N + bCol + wc * 32 + seg * 8] = v;
    }
  } else {
    // fused combine: each expert row -> token s with gate g; out[s] += g * (acc + bias)
#pragma unroll
    for (int mt = 0; mt < 4; ++mt)
#pragma unroll
      for (int r = 0; r < 4; ++r) {
        int grow = e * RA + bRow + wr * 64 + mt * 16 + q * 4 + r;
        int s = row_src[grow];
        if (s < 0) continue;
        float g = row_gate[grow];
#pragma unroll
        for (int nt = 0; nt < 2; ++nt) {
          float v = acc[mt][nt][r] + bv[nt];
          atomicAdd(out + (size_t)s * N + bCol + wc * 32 + nt * 16 + r16, g * v);
        }
      }
  }
}

// ---------------- l_aux: deterministic single-block reduction ----------------
__global__ __launch_bounds__(256) void aux_kernel(
    const float* __restrict__ scores, const int* __restrict__ topk_ids,
    float* __restrict__ laux_out)
{
  __shared__ float red[256];
  __shared__ float msum[8], csum[8];
  int t = threadIdx.x;
  float me[8], ce[8];
#pragma unroll
  for (int e = 0; e < 8; ++e) { me[e] = 0.f; ce[e] = 0.f; }
  for (int s = t; s < S_TOK; s += 256) {
#pragma unroll
    for (int e = 0; e < 8; ++e) me[e] += scores[s * 8 + e];
    int top = topk_ids[s * 2];
#pragma unroll
    for (int e = 0; e < 8; ++e) ce[e] += (top == e) ? 1.f : 0.f;
  }
  for (int e = 0; e < 8; ++e) {
    red[t] = me[e]; __syncthreads();
    for (int off = 128; off; off >>= 1) { if (t < off) red[t] += red[t + off]; __syncthreads(); }
    if (t == 0) msum[e] = red[0];
    __syncthreads();
  }
  for (int e = 0; e < 8; ++e) {
    red[t] = ce[e]; __syncthreads();
    for (int off = 128; off; off >>= 1) { if (t < off) red[t] += red[t + off]; __syncthreads(); }
    if (t == 0) csum[e] = red[0];
    __syncthreads();
  }
  if (t == 0) {
    float l = 0.f;
#pragma unroll
    for (int e = 0; e < 8; ++e)
      l += (msum[e] / (float)S_TOK) * (csum[e] / (float)S_TOK);
    laux_out[0] = l * (float)NEXP;
  }
}

extern "C" void kernel_launch(void* const* d_in, const int* in_sizes, int n_in,
                              void* d_out, int out_size, void* d_ws, size_t ws_size,
                              hipStream_t stream) {
  const float* x     = (const float*)d_in[0];
  const float* wg    = (const float*)d_in[1];
  const float* fc1_w = (const float*)d_in[2];
  const float* fc1_b = (const float*)d_in[3];
  const float* fc2_w = (const float*)d_in[4];
  const float* fc2_b = (const float*)d_in[5];
  float* out = (float*)d_out;

  // workspace carve-out (~208 MB total)
  char* ws = (char*)d_ws;
  size_t off = 0;
  auto alloc = [&](size_t b) { size_t o = off; off += (b + 255) & ~(size_t)255; return o; };
  unsigned short* fc1T = (unsigned short*)(ws + alloc((size_t)NEXP * HDIM * MDIM * 2)); // [E,H,M] bf16
  unsigned short* fc2T = (unsigned short*)(ws + alloc((size_t)NEXP * MDIM * HDIM * 2)); // [E,M,H] bf16
  unsigned short* y    = (unsigned short*)(ws + alloc((size_t)NEXP * CAP * MDIM * 2));  // [E*C,M] bf16
  unsigned short* h    = (unsigned short*)(ws + alloc((size_t)NEXP * CAP * HDIM * 2));  // [E*C,H] bf16
  float* scores        = (float*)(ws + alloc((size_t)S_TOK * 8 * 4));
  int*   topk          = (int*)(ws + alloc((size_t)S_TOK * 2 * 4));
  float* gates         = (float*)(ws + alloc((size_t)S_TOK * 2 * 4));
  int*   row_src       = (int*)(ws + alloc((size_t)NEXP * CAP * 4));
  float* row_gate      = (float*)(ws + alloc((size_t)NEXP * CAP * 4));

  // zero-init output (combine epilogue accumulates atomically into it)
  hipMemsetAsync(d_out, 0, (size_t)out_size * 4, stream);

  // Both weight transposes BEFORE GEMM1: nothing then streams between GEMM1's h-writes
  // and GEMM2's h-reads (L3 live set during GEMM1: fc1T+fc2T+y+h ~ 208MB < 256MB).
  convT_kernel<<<dim3(HDIM / 64, MDIM / 64, NEXP), 256, 0, stream>>>(fc1_w, fc1T, MDIM, HDIM);
  convT_kernel<<<dim3(MDIM / 64, HDIM / 64, NEXP), 256, 0, stream>>>(fc2_w, fc2T, HDIM, MDIM);

  gating_kernel<<<dim3(S_TOK / 4), 256, 0, stream>>>(x, wg, scores, topk, gates);
  assign_kernel<<<dim3(1), 1024, 0, stream>>>(topk, gates, row_src, row_gate);
  dispatch_kernel<<<dim3(NEXP * CAP / 2), 256, 0, stream>>>(x, row_src, y);

  // h = relu(y @ fc1_w + fc1_b): RA=C, N=H, K=M; grid 32x8x8 -> 2048 blocks, 512 thr
  gemm_bt<<<dim3(2048), 512, 0, stream>>>(y, fc1T, fc1_b, h, CAP, HDIM, MDIM, 1, 31, 5,
                                          0, nullptr, nullptr, nullptr);

  // out[token] += gate * (h @ fc2_w + fc2_b): RA=C, N=M, K=H; grid 8x8x8 -> 512 blocks, 512 thr
  gemm_bt<<<dim3(512), 512, 0, stream>>>(h, fc2T, fc2_b, nullptr, CAP, MDIM, HDIM, 0, 7, 3,
                                         1, row_src, row_gate, out);

  aux_kernel<<<dim3(1), 256, 0, stream>>>(scores, topk, out + (size_t)S_TOK * MDIM);
}

// Round 5
// 513.534 us; speedup vs baseline: 1.1733x; 1.0120x over previous
//
#include <hip/hip_runtime.h>
#include <stdint.h>

// Problem constants (S,M,H,E fixed by setup_inputs; C = ceil(K*S/E) aligned to 4 = 1024)
#define S_TOK 4096
#define MDIM  1024
#define HDIM  4096
#define NEXP  8
#define CAP   1024

typedef __attribute__((ext_vector_type(4))) float f4;
typedef __attribute__((ext_vector_type(8))) short short8;
typedef __attribute__((ext_vector_type(4))) unsigned short us4;
typedef __attribute__((ext_vector_type(8))) unsigned short us8;

__device__ __forceinline__ unsigned short f2bf(float f) {
  union { float f; unsigned int u; } v; v.f = f;
  unsigned int u = v.u;
  unsigned int r = (u + 0x7FFFu + ((u >> 16) & 1u)) >> 16;  // RNE
  return (unsigned short)r;
}

// async global->LDS, 16B per lane; LDS dest = wave-uniform base + lane*16
__device__ __forceinline__ void async16(const unsigned short* gp, unsigned short* lp_wave_base) {
  __builtin_amdgcn_global_load_lds(
      (const __attribute__((address_space(1))) unsigned int*)gp,
      (__attribute__((address_space(3))) unsigned int*)lp_wave_base,
      16, 0, 0);
}

// ---------------- gating: logits (fp32), softmax, top-2, gates ----------------
__global__ __launch_bounds__(256) void gating_kernel(
    const float* __restrict__ x, const float* __restrict__ wg,
    float* __restrict__ scores, int* __restrict__ topk_ids,
    float* __restrict__ gates)
{
  int wave = threadIdx.x >> 6, lane = threadIdx.x & 63;
  int s = blockIdx.x * 4 + wave;
  const float* xs = x + (size_t)s * MDIM;
  float acc[8];
#pragma unroll
  for (int e = 0; e < 8; ++e) acc[e] = 0.f;
#pragma unroll
  for (int j = 0; j < 4; ++j) {
    f4 xv = *(const f4*)(xs + j * 256 + lane * 4);
#pragma unroll
    for (int i = 0; i < 4; ++i) {
      int m = j * 256 + lane * 4 + i;
      const f4* w = (const f4*)(wg + (size_t)m * 8);
      f4 w0 = w[0], w1 = w[1];
      acc[0] += xv[i] * w0[0]; acc[1] += xv[i] * w0[1];
      acc[2] += xv[i] * w0[2]; acc[3] += xv[i] * w0[3];
      acc[4] += xv[i] * w1[0]; acc[5] += xv[i] * w1[1];
      acc[6] += xv[i] * w1[2]; acc[7] += xv[i] * w1[3];
    }
  }
#pragma unroll
  for (int e = 0; e < 8; ++e) {
    float v = acc[e];
    for (int off = 32; off; off >>= 1) v += __shfl_xor(v, off, 64);
    acc[e] = v;
  }
  if (lane == 0) {
    float mx = acc[0];
#pragma unroll
    for (int e = 1; e < 8; ++e) mx = fmaxf(mx, acc[e]);
    float p[8], tot = 0.f;
#pragma unroll
    for (int e = 0; e < 8; ++e) { p[e] = expf(acc[e] - mx); tot += p[e]; }
    float inv = 1.f / tot;
#pragma unroll
    for (int e = 0; e < 8; ++e) { p[e] *= inv; scores[s * 8 + e] = p[e]; }
    // top-2 with lowest-index tie-break (strict >), matching lax.top_k
    int i0 = 0;
#pragma unroll
    for (int e = 1; e < 8; ++e) if (p[e] > p[i0]) i0 = e;
    int i1 = -1;
#pragma unroll
    for (int e = 0; e < 8; ++e) {
      if (e == i0) continue;
      if (i1 < 0 || p[e] > p[i1]) i1 = e;
    }
    float v0 = p[i0], v1 = p[i1];
    float den = fmaxf(v0 + v1, 1e-7f);
    topk_ids[s * 2] = i0; topk_ids[s * 2 + 1] = i1;
    gates[s * 2] = v0 / den; gates[s * 2 + 1] = v1 / den;
  }
}

// ---------- assignment: exact ordered capacity scan (k-major over 8192 entries) ----------
// Outputs per expert-row: row_src (source token or -1), row_gate (combine weight).
__global__ __launch_bounds__(1024) void assign_kernel(
    const int* __restrict__ topk_ids, const float* __restrict__ gates,
    int* __restrict__ row_src, float* __restrict__ row_gate)
{
  __shared__ unsigned long long sc0[1024], sc1[1024];
  int t = threadIdx.x;
#pragma unroll
  for (int j = 0; j < 8; ++j) row_src[t * 8 + j] = -1;  // all 8192 rows

  int e8[8];
  unsigned long long c0 = 0, c1 = 0;
  int base = t * 8;
#pragma unroll
  for (int j = 0; j < 8; ++j) {
    int i = base + j;
    int k = i >> 12, s = i & 4095;     // i = k*4096 + s (k-major = reference offset order)
    int e = topk_ids[s * 2 + k];
    e8[j] = e;
    if (e < 4) c0 += 1ull << (16 * e); else c1 += 1ull << (16 * (e - 4));
  }
  sc0[t] = c0; sc1[t] = c1;
  __syncthreads();
  for (int off = 1; off < 1024; off <<= 1) {
    unsigned long long a0 = 0, a1 = 0;
    if (t >= off) { a0 = sc0[t - off]; a1 = sc1[t - off]; }
    __syncthreads();
    sc0[t] += a0; sc1[t] += a1;
    __syncthreads();
  }
  unsigned long long r0 = 0, r1 = 0;
  if (t > 0) { r0 = sc0[t - 1]; r1 = sc1[t - 1]; }
#pragma unroll
  for (int j = 0; j < 8; ++j) {
    int i = base + j;
    int k = i >> 12, s = i & 4095;
    int e = e8[j];
    int loc = (e < 4) ? (int)((r0 >> (16 * e)) & 0xFFFFull)
                      : (int)((r1 >> (16 * (e - 4))) & 0xFFFFull);
    if (e < 4) r0 += 1ull << (16 * e); else r1 += 1ull << (16 * (e - 4));
    if (loc < CAP) {
      int flat = e * CAP + loc;
      row_src[flat] = s;
      row_gate[flat] = gates[s * 2 + k];
    }
  }
}

// ---------------- dispatch: y[row] = bf16(x[src]) or zeros; 2 rows per block ----------------
__global__ __launch_bounds__(256) void dispatch_kernel(
    const float* __restrict__ x, const int* __restrict__ row_src,
    unsigned short* __restrict__ y)
{
  int r = blockIdx.x * 2 + (threadIdx.x >> 7);
  int s = row_src[r];
  int m0 = (threadIdx.x & 127) * 8;
  us8 o;
  if (s >= 0) {
    f4 v0 = *(const f4*)(x + (size_t)s * MDIM + m0);
    f4 v1 = *(const f4*)(x + (size_t)s * MDIM + m0 + 4);
#pragma unroll
    for (int i = 0; i < 4; ++i) { o[i] = f2bf(v0[i]); o[4 + i] = f2bf(v1[i]); }
  } else {
#pragma unroll
    for (int i = 0; i < 8; ++i) o[i] = 0;
  }
  *(us8*)(y + (size_t)r * MDIM + m0) = o;
}

// -------- weight convert+transpose: in [E,R,Cc] fp32 -> out [E,Cc,R] bf16 --------
// 64x64 tile staged as fp32 in LDS (stride 68 words, f4 16B-aligned bank-balanced writes);
// transposed b32 reads + convert + us8 (16B) coalesced stores.
// Weight reads are NON-TEMPORAL (`nt`): fp32 weights are stream-once; keep them from
// evicting the live L3 set that the GEMMs depend on. (r2: ~-44us total vs plain loads.)
__global__ __launch_bounds__(256) void convT_kernel(
    const float* __restrict__ in, unsigned short* __restrict__ out,
    int R, int Cc)
{
  __shared__ float tile[64 * 68];
  int e = blockIdx.z;
  int c0 = blockIdx.x * 64, r0 = blockIdx.y * 64;
  int t = threadIdx.x;
  const float* ine = in + (size_t)e * R * Cc;
  unsigned short* oute = out + (size_t)e * Cc * R;

  int cg = t & 15, rr = t >> 4;  // load map: 16 col-groups of 4 floats x 16 rows
#pragma unroll
  for (int p = 0; p < 4; ++p) {
    int r = rr + 16 * p;
    f4 v = __builtin_nontemporal_load(
        (const f4*)(ine + (size_t)(r0 + r) * Cc + c0 + cg * 4));
    *(f4*)&tile[r * 68 + cg * 4] = v;
  }
  __syncthreads();
  int c = t >> 3, rb = t & 7;    // store map: 32 cols x 8 r-chunks per pass
#pragma unroll
  for (int p = 0; p < 2; ++p) {
    int cc = c + 32 * p;
    us8 o;
#pragma unroll
    for (int i = 0; i < 8; ++i) o[i] = f2bf(tile[(rb * 8 + i) * 68 + cc]);
    *(us8*)(oute + (size_t)(c0 + cc) * R + r0 + rb * 8) = o;
  }
}

// ---------------- bf16 MFMA GEMM, B^T operand, expert-batched, XCD-swizzled ----------------
// 8 waves (512 threads) per 128x128 tile; wave grid 2(M)x4(N), 64x32 sub-tile per wave.
// K-loop is ISSUE-EARLY double-buffered (T3-minimum): STAGE(t+1) -> COMPUTE(t) -> sync.
// The single __syncthreads per K-step drains vmcnt AFTER the compute phase, so the
// prefetched loads have the whole compute (~700cyc) in flight instead of stalling the
// block cold (r4 measured the stage->sync->compute order at the 2-phase ceiling: 656 TF,
// MfmaUtil 27%, nothing saturated). Named bufA/bufB (compile-time LDS addrs, unrolled
// 2-step body) so alias analysis can't insert a conservative early vmcnt(0).
// 1D grid; e = lin&7 pins each expert's blocks to one XCD (L2 locality heuristic).
// fuse=0: out bf16 = (relu? max(v+b,0) : v+b), LDS-staged us8 stores.
// fuse=1: combine epilogue: atomicAdd(out[token, col], gate * (v+b)) via row_src/row_gate.
__global__ __launch_bounds__(512, 4) void gemm_bt(
    const unsigned short* __restrict__ A, const unsigned short* __restrict__ Bt,
    const float* __restrict__ bias, unsigned short* __restrict__ Cout,
    int RA, int N, int K, int relu, int gxmask, int gxshift,
    int fuse, const int* __restrict__ row_src, const float* __restrict__ row_gate,
    float* __restrict__ out)
{
  int lin = blockIdx.x;
  int e = lin & 7;
  int tt = lin >> 3;
  int bCol = (tt & gxmask) * 128;
  int bRow = (tt >> gxshift) * 128;

  const unsigned short* Ae = A  + (size_t)e * RA * K;
  const unsigned short* Be = Bt + (size_t)e * N  * K;
  const float* be = bias + (size_t)e * N;

  // 64KB: two K-step buffers, each = A[128][64] (8192 shorts) + B[128][64] (8192 shorts).
  // Within a buffer: ks-half at ks*4096, linear [row][k] stride-32 layout.
  __shared__ __align__(16) unsigned short LDSbuf[32768];
  unsigned short* bufA = LDSbuf;
  unsigned short* bufB = LDSbuf + 16384;

  int tid = threadIdx.x;
  int lane = tid & 63, wave = tid >> 6;      // 8 waves
  int wr = wave >> 2, wc = wave & 3;         // 2 (M) x 4 (N)
  int q = lane >> 4, r16 = lane & 15;

  // staging map: chunk ci in [0,512): row=ci>>2, k-offset=(ci&3)*8;
  // LDS dest shorts = wave*512 + lane*8 == row*32 + c8 (matches layout; wave-uniform base).
  int ci = wave * 64 + lane;
  int srow = ci >> 2, sc8 = (ci & 3) * 8;
  const unsigned short* agp = Ae + (size_t)(bRow + srow) * K + sc8;
  const unsigned short* bgp = Be + (size_t)(bCol + srow) * K + sc8;

  f4 acc[4][2] = {};

  auto STAGE = [&](int k0, unsigned short* buf) {
#pragma unroll
    for (int ks = 0; ks < 2; ++ks) {
      async16(agp + k0 + ks * 32, buf + ks * 4096 + wave * 512);
      async16(bgp + k0 + ks * 32, buf + 8192 + ks * 4096 + wave * 512);
    }
  };
  auto COMPUTE = [&](const unsigned short* buf) {
#pragma unroll
    for (int ks = 0; ks < 2; ++ks) {
      short8 af[4], bf[2];
#pragma unroll
      for (int mt = 0; mt < 4; ++mt)
        af[mt] = *(const short8*)&buf[ks * 4096 + (wr * 64 + mt * 16 + r16) * 32 + q * 8];
#pragma unroll
      for (int nt = 0; nt < 2; ++nt)
        bf[nt] = *(const short8*)&buf[8192 + ks * 4096 + (wc * 32 + nt * 16 + r16) * 32 + q * 8];
#pragma unroll
      for (int mt = 0; mt < 4; ++mt)
#pragma unroll
        for (int nt = 0; nt < 2; ++nt)
          acc[mt][nt] = __builtin_amdgcn_mfma_f32_16x16x32_bf16(af[mt], bf[nt], acc[mt][nt], 0, 0, 0);
    }
  };

  int nt = K >> 6;  // K-steps of 64 (nt even: 16 or 64 here)
  STAGE(0, bufA);
  __syncthreads();                       // tile 0 resident
  int t = 0;
  for (; t < nt - 2; t += 2) {
    STAGE((t + 1) << 6, bufB);           // prefetch t+1 (in flight across compute)
    COMPUTE(bufA);                       // compute t
    __syncthreads();                     // drain t+1 loads + barrier
    STAGE((t + 2) << 6, bufA);           // prefetch t+2 (overwrites computed tile t)
    COMPUTE(bufB);                       // compute t+1
    __syncthreads();
  }
  // tail: tiles nt-2 (bufA, already staged), nt-1
  STAGE((nt - 1) << 6, bufB);
  COMPUTE(bufA);
  __syncthreads();
  COMPUTE(bufB);
  __syncthreads();                       // LDS reused by !fuse epilogue

  // C/D layout: col=lane&15, row=quad*4+reg (verified m89/m91)
  float bv[2];
#pragma unroll
  for (int nt2 = 0; nt2 < 2; ++nt2) bv[nt2] = be[bCol + wc * 32 + nt2 * 16 + r16];

  if (!fuse) {
    // stage wave's 64x32 bf16 tile in its private 4KB LDS slice, then 16B stores
    unsigned short* ep = LDSbuf + wave * 2048;
#pragma unroll
    for (int mt = 0; mt < 4; ++mt)
#pragma unroll
      for (int nt2 = 0; nt2 < 2; ++nt2)
#pragma unroll
        for (int r = 0; r < 4; ++r) {
          float v = acc[mt][nt2][r] + bv[nt2];
          if (relu) v = fmaxf(v, 0.f);
          ep[(mt * 16 + q * 4 + r) * 32 + nt2 * 16 + r16] = f2bf(v);
        }
    // 64 rows x 32 cols: 4 passes of 64 lanes x 16B
#pragma unroll
    for (int pass = 0; pass < 4; ++pass) {
      int row = pass * 16 + (lane >> 2);
      int seg = lane & 3;
      us8 v = *(const us8*)&ep[row * 32 + seg * 8];
      *(us8*)&Cout[((size_t)e * RA + bRow + wr * 64 + row) * N + bCol + wc * 32 + seg * 8] = v;
    }
  } else {
    // fused combine: each expert row -> token s with gate g; out[s] += g * (acc + bias)
#pragma unroll
    for (int mt = 0; mt < 4; ++mt)
#pragma unroll
      for (int r = 0; r < 4; ++r) {
        int grow = e * RA + bRow + wr * 64 + mt * 16 + q * 4 + r;
        int s = row_src[grow];
        if (s < 0) continue;
        float g = row_gate[grow];
#pragma unroll
        for (int nt2 = 0; nt2 < 2; ++nt2) {
          float v = acc[mt][nt2][r] + bv[nt2];
          atomicAdd(out + (size_t)s * N + bCol + wc * 32 + nt2 * 16 + r16, g * v);
        }
      }
  }
}

// ---------------- l_aux: deterministic single-block reduction ----------------
__global__ __launch_bounds__(256) void aux_kernel(
    const float* __restrict__ scores, const int* __restrict__ topk_ids,
    float* __restrict__ laux_out)
{
  __shared__ float red[256];
  __shared__ float msum[8], csum[8];
  int t = threadIdx.x;
  float me[8], ce[8];
#pragma unroll
  for (int e = 0; e < 8; ++e) { me[e] = 0.f; ce[e] = 0.f; }
  for (int s = t; s < S_TOK; s += 256) {
#pragma unroll
    for (int e = 0; e < 8; ++e) me[e] += scores[s * 8 + e];
    int top = topk_ids[s * 2];
#pragma unroll
    for (int e = 0; e < 8; ++e) ce[e] += (top == e) ? 1.f : 0.f;
  }
  for (int e = 0; e < 8; ++e) {
    red[t] = me[e]; __syncthreads();
    for (int off = 128; off; off >>= 1) { if (t < off) red[t] += red[t + off]; __syncthreads(); }
    if (t == 0) msum[e] = red[0];
    __syncthreads();
  }
  for (int e = 0; e < 8; ++e) {
    red[t] = ce[e]; __syncthreads();
    for (int off = 128; off; off >>= 1) { if (t < off) red[t] += red[t + off]; __syncthreads(); }
    if (t == 0) csum[e] = red[0];
    __syncthreads();
  }
  if (t == 0) {
    float l = 0.f;
#pragma unroll
    for (int e = 0; e < 8; ++e)
      l += (msum[e] / (float)S_TOK) * (csum[e] / (float)S_TOK);
    laux_out[0] = l * (float)NEXP;
  }
}

extern "C" void kernel_launch(void* const* d_in, const int* in_sizes, int n_in,
                              void* d_out, int out_size, void* d_ws, size_t ws_size,
                              hipStream_t stream) {
  const float* x     = (const float*)d_in[0];
  const float* wg    = (const float*)d_in[1];
  const float* fc1_w = (const float*)d_in[2];
  const float* fc1_b = (const float*)d_in[3];
  const float* fc2_w = (const float*)d_in[4];
  const float* fc2_b = (const float*)d_in[5];
  float* out = (float*)d_out;

  // workspace carve-out (~208 MB total)
  char* ws = (char*)d_ws;
  size_t off = 0;
  auto alloc = [&](size_t b) { size_t o = off; off += (b + 255) & ~(size_t)255; return o; };
  unsigned short* fc1T = (unsigned short*)(ws + alloc((size_t)NEXP * HDIM * MDIM * 2)); // [E,H,M] bf16
  unsigned short* fc2T = (unsigned short*)(ws + alloc((size_t)NEXP * MDIM * HDIM * 2)); // [E,M,H] bf16
  unsigned short* y    = (unsigned short*)(ws + alloc((size_t)NEXP * CAP * MDIM * 2));  // [E*C,M] bf16
  unsigned short* h    = (unsigned short*)(ws + alloc((size_t)NEXP * CAP * HDIM * 2));  // [E*C,H] bf16
  float* scores        = (float*)(ws + alloc((size_t)S_TOK * 8 * 4));
  int*   topk          = (int*)(ws + alloc((size_t)S_TOK * 2 * 4));
  float* gates         = (float*)(ws + alloc((size_t)S_TOK * 2 * 4));
  int*   row_src       = (int*)(ws + alloc((size_t)NEXP * CAP * 4));
  float* row_gate      = (float*)(ws + alloc((size_t)NEXP * CAP * 4));

  // zero-init output (combine epilogue accumulates atomically into it)
  hipMemsetAsync(d_out, 0, (size_t)out_size * 4, stream);

  // Both weight transposes BEFORE GEMM1 (nt reads; r4: h still streams from HBM, but
  // fc2T stays L3-hot for GEMM2's B operand).
  convT_kernel<<<dim3(HDIM / 64, MDIM / 64, NEXP), 256, 0, stream>>>(fc1_w, fc1T, MDIM, HDIM);
  convT_kernel<<<dim3(MDIM / 64, HDIM / 64, NEXP), 256, 0, stream>>>(fc2_w, fc2T, HDIM, MDIM);

  gating_kernel<<<dim3(S_TOK / 4), 256, 0, stream>>>(x, wg, scores, topk, gates);
  assign_kernel<<<dim3(1), 1024, 0, stream>>>(topk, gates, row_src, row_gate);
  dispatch_kernel<<<dim3(NEXP * CAP / 2), 256, 0, stream>>>(x, row_src, y);

  // h = relu(y @ fc1_w + fc1_b): RA=C, N=H, K=M; grid 32x8x8 -> 2048 blocks, 512 thr
  gemm_bt<<<dim3(2048), 512, 0, stream>>>(y, fc1T, fc1_b, h, CAP, HDIM, MDIM, 1, 31, 5,
                                          0, nullptr, nullptr, nullptr);

  // out[token] += gate * (h @ fc2_w + fc2_b): RA=C, N=M, K=H; grid 8x8x8 -> 512 blocks, 512 thr
  gemm_bt<<<dim3(512), 512, 0, stream>>>(h, fc2T, fc2_b, nullptr, CAP, MDIM, HDIM, 0, 7, 3,
                                         1, row_src, row_gate, out);

  aux_kernel<<<dim3(1), 256, 0, stream>>>(scores, topk, out + (size_t)S_TOK * MDIM);
}